// Round 7
// baseline (6005.251 us; speedup 1.0000x reference)
//
#include <hip/hip_runtime.h>

typedef __attribute__((ext_vector_type(8))) short short8;
typedef __attribute__((ext_vector_type(4))) float f32x4;

#define MFMA16 __builtin_amdgcn_mfma_f32_16x16x32_bf16

__device__ __forceinline__ unsigned short f2bf(float f){
  union { float f; unsigned int u; } v; v.f = f;
  unsigned int u = v.u + 0x7fffu + ((v.u >> 16) & 1u);  // RNE
  return (unsigned short)(u >> 16);
}
__device__ __forceinline__ float lo2f(unsigned int u){ union { unsigned int u; float f; } v; v.u = u << 16; return v.f; }
__device__ __forceinline__ float hi2f(unsigned int u){ union { unsigned int u; float f; } v; v.u = u & 0xffff0000u; return v.f; }

// ---------------- ws layout (weights) ----------------
constexpr size_t WQKV_HSTR = 768*256;                       // per-head [768][256] rows: Q 0-255, K 256-511, V 512-767
constexpr size_t W1T_OFF   = 8*WQKV_HSTR;                   // 8 x [256][512]
constexpr size_t W1T_HSTR  = 512*256;
constexpr size_t W2T_OFF   = W1T_OFF + 8*W1T_HSTR;          // 8 x [256][256]
constexpr size_t W2T_HSTR  = 256*256;
constexpr size_t OQKV_OFF  = W2T_OFF + 8*W2T_HSTR;          // [768][2048]
constexpr size_t OW1_OFF   = OQKV_OFF + (size_t)768*2048;   // [256][2304]
constexpr size_t OW2_OFF   = OW1_OFF + (size_t)256*2304;    // [256][256]
constexpr size_t WT_ELEMS  = OW2_OFF + (size_t)256*256;
constexpr size_t XP_OFFB   = (WT_ELEMS*2 + 255) & ~(size_t)255;
constexpr size_t XP_BYTES  = (size_t)131072*256*2;          // xpf: fragment-tile order
constexpr size_t FEATS_OFFB = XP_OFFB + XP_BYTES;

// fragment-tile addr within a [rows][256] region (16-row x 32-col tiles)
__device__ __forceinline__ int fragA(int row, int col){
  return ((row >> 4)*8 + (col >> 5))*512 + (row & 15)*32 + (col & 31);
}

// ---------------- prep: transpose weights to bf16 [N][K] ----------------
__global__ void k_transpose(const float* __restrict__ src, unsigned short* __restrict__ dst,
                            int K, int N, long long srcStride, long long dstStride){
  const int i = blockIdx.x*256 + threadIdx.x;
  const int b = blockIdx.y;
  const int n = i / K, k = i - n*K;
  dst[(size_t)b*dstStride + i] = f2bf(src[(size_t)b*srcStride + (size_t)k*N + n]);
}

// ---------------- xpf = bf16(x + pos) in fragment-tile order ----------------
__global__ void k_xp(const float* __restrict__ x, const float* __restrict__ pos,
                     unsigned short* __restrict__ xpf){
  const size_t eidx = ((size_t)blockIdx.x*256 + threadIdx.x) * 8;
  const int rb   = (int)(eidx >> 12);
  const int rem  = (int)(eidx & 4095);
  const int kk   = rem >> 9;
  const int rem2 = rem & 511;
  const int l16  = rem2 >> 5;
  const int off  = rem2 & 31;
  const size_t row = (size_t)rb*16 + l16;
  const int col = kk*32 + off;
  const int t = (int)(row & 7);
  float4 a0 = *(const float4*)(x + row*256 + col);
  float4 a1 = *(const float4*)(x + row*256 + col + 4);
  float4 p0 = *(const float4*)(pos + t*256 + col);
  float4 p1 = *(const float4*)(pos + t*256 + col + 4);
  short8 o;
  o[0]=(short)f2bf(a0.x+p0.x); o[1]=(short)f2bf(a0.y+p0.y);
  o[2]=(short)f2bf(a0.z+p0.z); o[3]=(short)f2bf(a0.w+p0.w);
  o[4]=(short)f2bf(a1.x+p1.x); o[5]=(short)f2bf(a1.y+p1.y);
  o[6]=(short)f2bf(a1.z+p1.z); o[7]=(short)f2bf(a1.w+p1.w);
  *(short8*)(xpf + eidx) = o;
}

// ==================== per-head-group fused kernel ====================
// 64 rows, 8 waves, 4 heads per block (blockIdx.y selects head group).
// A from xpf (frag-order global, L1/L2-hot, reused across 4 heads);
// B from global (L2-hot panels); feats HEAD-MAJOR [8][R][256] -> each
// block writes contiguous 32KB per head. LDS 66.5KB -> 2 blocks/CU.
__global__ __launch_bounds__(512, 4) void k_head(
    const unsigned short* __restrict__ xpf,
    const unsigned short* __restrict__ WT,
    const float* __restrict__ hb1, const float* __restrict__ hb2,
    unsigned short* __restrict__ feats, long long fhstr)
{
  __shared__ __align__(16) unsigned short TfA[16384];  // frag: Q -> V -> h1
  __shared__ __align__(16) unsigned short TfB[16384];  // frag: K -> attn_out
  __shared__ float aw[8][64];

  const int r0   = blockIdx.x * 64;              // chunk-local
  const int hg   = blockIdx.y * 4;
  const int tid  = threadIdx.x;
  const int wave = tid >> 6;
  const int lane = tid & 63;
  const int l16  = lane & 15;
  const int lq   = lane >> 4;
  const unsigned short* xA = xpf + (size_t)(r0 >> 4) * 4096;   // A-frag base

  for (int h = hg; h < hg + 4; h++){
    const unsigned short* Wh = WT + (size_t)h * WQKV_HSTR;

    // ---- P1 QK: [64,256]@[256,512] -> TfA (Q), TfB (K)
    {
      f32x4 acc[4][4];
      #pragma unroll
      for (int m = 0; m < 4; m++)
        #pragma unroll
        for (int n = 0; n < 4; n++) acc[m][n] = (f32x4){0.f,0.f,0.f,0.f};
      const unsigned short* b0 = Wh + (size_t)(wave*64 + l16)*256 + lq*8;
      #pragma unroll
      for (int kk = 0; kk < 8; kk++){
        short8 a[4];
        #pragma unroll
        for (int m = 0; m < 4; m++) a[m] = *(const short8*)(xA + m*4096 + kk*512 + l16*32 + lq*8);
        #pragma unroll
        for (int n = 0; n < 4; n++){
          short8 b = *(const short8*)(b0 + n*4096 + kk*32);
          #pragma unroll
          for (int m = 0; m < 4; m++) acc[m][n] = MFMA16(a[m], b, acc[m][n], 0,0,0);
        }
      }
      unsigned short* dst = (wave < 4) ? TfA : TfB;
      const int cb = (wave & 3) * 64;
      #pragma unroll
      for (int n = 0; n < 4; n++){
        const int col = cb + n*16 + l16;
        #pragma unroll
        for (int m = 0; m < 4; m++)
          #pragma unroll
          for (int r = 0; r < 4; r++)
            dst[fragA(m*16 + lq*4 + r, col)] = f2bf(acc[m][n][r]);
      }
    }
    __syncthreads();

    // ---- P2 scores + causal softmax (wave <-> batch group, lane = (t,s))
    {
      const int g = wave;
      const int t = lane >> 3, s = lane & 7;
      const int qrow = g*8 + t, krow = g*8 + s;
      float e = 0.f;
      #pragma unroll
      for (int kk = 0; kk < 8; kk++){
        #pragma unroll
        for (int j = 0; j < 4; j++){
          union { short8 v; unsigned int u[4]; } qa, kb;
          qa.v = *(const short8*)(TfA + ((qrow>>4)*8 + kk)*512 + (qrow&15)*32 + j*8);
          kb.v = *(const short8*)(TfB + ((krow>>4)*8 + kk)*512 + (krow&15)*32 + j*8);
          #pragma unroll
          for (int q = 0; q < 4; q++){
            e = fmaf(lo2f(qa.u[q]), lo2f(kb.u[q]), e);
            e = fmaf(hi2f(qa.u[q]), hi2f(kb.u[q]), e);
          }
        }
      }
      e *= 0.0625f;                    // 1/sqrt(256)
      if (s > t) e = -1e30f;           // causal
      float mx = fmaxf(e, __shfl_xor(e, 1));
      mx = fmaxf(mx, __shfl_xor(mx, 2));
      mx = fmaxf(mx, __shfl_xor(mx, 4));
      float p = (s <= t) ? __expf(e - mx) : 0.f;
      float sum = p;
      sum += __shfl_xor(sum, 1);
      sum += __shfl_xor(sum, 2);
      sum += __shfl_xor(sum, 4);
      aw[g][lane] = p / sum;
    }
    __syncthreads();   // Q/K reads done; V overwrites TfA

    // ---- P3 V: [64,256]@[256,256] -> TfA
    {
      f32x4 acc[4][2];
      #pragma unroll
      for (int m = 0; m < 4; m++){ acc[m][0]=(f32x4){0.f,0.f,0.f,0.f}; acc[m][1]=(f32x4){0.f,0.f,0.f,0.f}; }
      const unsigned short* b0 = Wh + (size_t)(512 + wave*32 + l16)*256 + lq*8;
      #pragma unroll
      for (int kk = 0; kk < 8; kk++){
        short8 a[4];
        #pragma unroll
        for (int m = 0; m < 4; m++) a[m] = *(const short8*)(xA + m*4096 + kk*512 + l16*32 + lq*8);
        #pragma unroll
        for (int n = 0; n < 2; n++){
          short8 b = *(const short8*)(b0 + n*4096 + kk*32);
          #pragma unroll
          for (int m = 0; m < 4; m++) acc[m][n] = MFMA16(a[m], b, acc[m][n], 0,0,0);
        }
      }
      #pragma unroll
      for (int n = 0; n < 2; n++){
        const int col = wave*32 + n*16 + l16;
        #pragma unroll
        for (int m = 0; m < 4; m++)
          #pragma unroll
          for (int r = 0; r < 4; r++)
            TfA[fragA(m*16 + lq*4 + r, col)] = f2bf(acc[m][n][r]);
      }
    }
    __syncthreads();

    // ---- P4 PV: attn @ V -> TfB (attn_out; K dead)
    {
      const int g = wave;
      const int t = lane >> 3, c8 = lane & 7;
      float o[32];
      #pragma unroll
      for (int j = 0; j < 32; j++) o[j] = 0.f;
      #pragma unroll
      for (int s = 0; s < 8; s++){
        const float w = aw[g][t*8 + s];
        const int vrow = g*8 + s;
        const unsigned short* Vr = TfA + ((vrow>>4)*8 + c8)*512 + (vrow&15)*32;
        #pragma unroll
        for (int jj = 0; jj < 4; jj++){
          union { short8 v; unsigned int u[4]; } vv;
          vv.v = *(const short8*)(Vr + jj*8);
          #pragma unroll
          for (int q = 0; q < 4; q++){
            o[jj*8 + 2*q]     = fmaf(w, lo2f(vv.u[q]), o[jj*8 + 2*q]);
            o[jj*8 + 2*q + 1] = fmaf(w, hi2f(vv.u[q]), o[jj*8 + 2*q + 1]);
          }
        }
      }
      const int trow = g*8 + t;
      unsigned short* Or = TfB + ((trow>>4)*8 + c8)*512 + (trow&15)*32;
      #pragma unroll
      for (int jj = 0; jj < 4; jj++){
        short8 v;
        #pragma unroll
        for (int q = 0; q < 8; q++) v[q] = (short)f2bf(o[jj*8 + q]);
        *(short8*)(Or + jj*8) = v;
      }
    }
    __syncthreads();

    // ---- P5 FFN1: cat(attn_out, xp) [64,512]@[512,256] -> h1 into TfA
    {
      const unsigned short* W = WT + W1T_OFF + (size_t)h*W1T_HSTR;  // [256][512]
      f32x4 acc[4][2];
      #pragma unroll
      for (int m = 0; m < 4; m++){ acc[m][0]=(f32x4){0.f,0.f,0.f,0.f}; acc[m][1]=(f32x4){0.f,0.f,0.f,0.f}; }
      const unsigned short* b0 = W + (size_t)(wave*32 + l16)*512 + lq*8;
      #pragma unroll
      for (int kk = 0; kk < 16; kk++){
        short8 a[4];
        if (kk < 8){
          #pragma unroll
          for (int m = 0; m < 4; m++) a[m] = *(const short8*)(TfB + (m*8 + kk)*512 + l16*32 + lq*8);
        } else {
          #pragma unroll
          for (int m = 0; m < 4; m++) a[m] = *(const short8*)(xA + m*4096 + (kk-8)*512 + l16*32 + lq*8);
        }
        #pragma unroll
        for (int n = 0; n < 2; n++){
          short8 b = *(const short8*)(b0 + n*8192 + kk*32);
          #pragma unroll
          for (int m = 0; m < 4; m++) acc[m][n] = MFMA16(a[m], b, acc[m][n], 0,0,0);
        }
      }
      #pragma unroll
      for (int n = 0; n < 2; n++){
        const int col = wave*32 + n*16 + l16;
        const float bv = hb1[(h<<8) + col];
        #pragma unroll
        for (int m = 0; m < 4; m++)
          #pragma unroll
          for (int r = 0; r < 4; r++)
            TfA[fragA(m*16 + lq*4 + r, col)] = f2bf(fmaxf(acc[m][n][r] + bv, 0.f));
      }
    }
    __syncthreads();

    // ---- P6 FFN2: [64,256]@[256,256] -> feats_h (contiguous region, direct)
    {
      const unsigned short* W = WT + W2T_OFF + (size_t)h*W2T_HSTR;
      f32x4 acc[4][2];
      #pragma unroll
      for (int m = 0; m < 4; m++){ acc[m][0]=(f32x4){0.f,0.f,0.f,0.f}; acc[m][1]=(f32x4){0.f,0.f,0.f,0.f}; }
      const unsigned short* b0 = W + (size_t)(wave*32 + l16)*256 + lq*8;
      #pragma unroll
      for (int kk = 0; kk < 8; kk++){
        short8 a[4];
        #pragma unroll
        for (int m = 0; m < 4; m++) a[m] = *(const short8*)(TfA + (m*8 + kk)*512 + l16*32 + lq*8);
        #pragma unroll
        for (int n = 0; n < 2; n++){
          short8 b = *(const short8*)(b0 + n*4096 + kk*32);
          #pragma unroll
          for (int m = 0; m < 4; m++) acc[m][n] = MFMA16(a[m], b, acc[m][n], 0,0,0);
        }
      }
      unsigned short* Fh = feats + (size_t)h*fhstr;
      #pragma unroll
      for (int n = 0; n < 2; n++){
        const int col = wave*32 + n*16 + l16;
        const float bv = hb2[(h<<8) + col];
        #pragma unroll
        for (int m = 0; m < 4; m++)
          #pragma unroll
          for (int r = 0; r < 4; r++)
            Fh[(size_t)(r0 + m*16 + lq*4 + r)*256 + col] = f2bf(acc[m][n][r] + bv);
      }
    }
    __syncthreads();   // TfA/TfB reuse by next head
  }
}

// ==================== output-layer attention ====================
__global__ __launch_bounds__(512, 4) void k_attn2(
    const unsigned short* __restrict__ qkv2, unsigned short* __restrict__ ao)
{
  __shared__ float aw[8][64];
  const int r0   = blockIdx.x * 64;
  const int tid  = threadIdx.x;
  const int wave = tid >> 6;
  const int lane = tid & 63;
  const int g = wave;
  {
    const int t = lane >> 3, s = lane & 7;
    const unsigned short* Qr = qkv2 + (size_t)(r0 + g*8 + t)*768;
    const unsigned short* Kr = qkv2 + (size_t)(r0 + g*8 + s)*768 + 256;
    float e = 0.f;
    #pragma unroll
    for (int c = 0; c < 256; c += 8){
      union { short8 v; unsigned int u[4]; } qa, kb;
      qa.v = *(const short8*)(Qr + c);
      kb.v = *(const short8*)(Kr + c);
      #pragma unroll
      for (int j = 0; j < 4; j++){
        e = fmaf(lo2f(qa.u[j]), lo2f(kb.u[j]), e);
        e = fmaf(hi2f(qa.u[j]), hi2f(kb.u[j]), e);
      }
    }
    e *= 0.0625f;
    if (s > t) e = -1e30f;
    float mx = fmaxf(e, __shfl_xor(e, 1));
    mx = fmaxf(mx, __shfl_xor(mx, 2));
    mx = fmaxf(mx, __shfl_xor(mx, 4));
    float p = (s <= t) ? __expf(e - mx) : 0.f;
    float sum = p;
    sum += __shfl_xor(sum, 1);
    sum += __shfl_xor(sum, 2);
    sum += __shfl_xor(sum, 4);
    aw[g][lane] = p / sum;
  }
  __syncthreads();
  {
    const int t = lane >> 3, c8 = lane & 7;
    float o[32];
    #pragma unroll
    for (int j = 0; j < 32; j++) o[j] = 0.f;
    #pragma unroll
    for (int s = 0; s < 8; s++){
      const float w = aw[g][t*8 + s];
      const unsigned short* Vr = qkv2 + (size_t)(r0 + g*8 + s)*768 + 512 + (c8 << 5);
      #pragma unroll
      for (int jj = 0; jj < 4; jj++){
        union { short8 v; unsigned int u[4]; } vv;
        vv.v = *(const short8*)(Vr + jj*8);
        #pragma unroll
        for (int q = 0; q < 4; q++){
          o[jj*8 + 2*q]     = fmaf(w, lo2f(vv.u[q]), o[jj*8 + 2*q]);
          o[jj*8 + 2*q + 1] = fmaf(w, hi2f(vv.u[q]), o[jj*8 + 2*q + 1]);
        }
      }
    }
    unsigned short* Or = ao + (size_t)(r0 + g*8 + t)*256 + (c8 << 5);
    #pragma unroll
    for (int jj = 0; jj < 4; jj++){
      short8 v;
      #pragma unroll
      for (int q = 0; q < 8; q++) v[q] = (short)f2bf(o[jj*8 + q]);
      *(short8*)(Or + jj*8) = v;
    }
  }
}

// ==================== tiled GEMM: C[M,N] = A @ B^T ====================
// A: k<K1 from A1 (row-major lda1); k>=K1 from A2. A2 is head-major
// [8][R][256] if hstr2>0 (region = k'>>8), else row-major lda2.
// 128x128 tile, 4 waves (2x2), BK=64, reg-staged double-buffered LDS.
// EPI: 0 = bf16 store; 1 = bias+relu bf16; 2 = bias f32.
template<int EPI>
__global__ __launch_bounds__(256, 2) void k_gemm(
    const unsigned short* __restrict__ A1, long long lda1, int K1,
    const unsigned short* __restrict__ A2, long long lda2, long long hstr2,
    const unsigned short* __restrict__ B, long long ldb, int K,
    const float* __restrict__ bias,
    void* __restrict__ Cv, long long ldc)
{
  __shared__ __align__(16) unsigned short SM[36864];   // 72KB: As[2][128*72] | Bs[2][128*72]
  unsigned short* As = SM;
  unsigned short* Bs = SM + 18432;

  const int tid  = threadIdx.x;
  const int wave = tid >> 6, lane = tid & 63;
  const int l16  = lane & 15, lq = lane >> 4;
  const int wm   = wave >> 1, wn = wave & 1;
  const size_t r0 = (size_t)blockIdx.x * 128;
  const int    c0 = blockIdx.y * 128;
  const int srow = tid >> 1, scol = (tid & 1) * 32;   // staging: 32 elems/thread

  f32x4 acc[4][4];
  #pragma unroll
  for (int m = 0; m < 4; m++)
    #pragma unroll
    for (int n = 0; n < 4; n++) acc[m][n] = (f32x4){0.f,0.f,0.f,0.f};

  const int KS = K >> 6;

  auto srcA = [&](int k0) -> const unsigned short* {
    if (k0 < K1) return A1 + (r0 + srow)*lda1 + k0 + scol;
    const int k2 = k0 - K1;
    if (hstr2 > 0) return A2 + (size_t)(k2 >> 8)*hstr2 + (r0 + srow)*256 + (k2 & 255) + scol;
    return A2 + (r0 + srow)*lda2 + k2 + scol;
  };

  // prologue: stage k0=0 into buf 0
  {
    const unsigned short* sa = srcA(0);
    const unsigned short* sb = B + (size_t)(c0 + srow)*ldb + scol;
    #pragma unroll
    for (int j = 0; j < 4; j++){
      *(short8*)(As + srow*72 + scol + j*8) = *(const short8*)(sa + j*8);
      *(short8*)(Bs + srow*72 + scol + j*8) = *(const short8*)(sb + j*8);
    }
  }
  __syncthreads();

  int cur = 0;
  for (int s2 = 0; s2 < KS; s2++){
    short8 ra[4], rb[4];
    const bool pf = (s2 + 1 < KS);
    if (pf){
      const int k0 = (s2 + 1) << 6;
      const unsigned short* sa = srcA(k0);
      const unsigned short* sb = B + (size_t)(c0 + srow)*ldb + k0 + scol;
      #pragma unroll
      for (int j = 0; j < 4; j++){ ra[j] = *(const short8*)(sa + j*8); rb[j] = *(const short8*)(sb + j*8); }
    }
    const unsigned short* Ab = As + cur*9216;
    const unsigned short* Bb = Bs + cur*9216;
    #pragma unroll
    for (int kk = 0; kk < 2; kk++){
      short8 af[4], bf[4];
      #pragma unroll
      for (int m = 0; m < 4; m++) af[m] = *(const short8*)(Ab + (wm*64 + m*16 + l16)*72 + kk*32 + lq*8);
      #pragma unroll
      for (int n = 0; n < 4; n++) bf[n] = *(const short8*)(Bb + (wn*64 + n*16 + l16)*72 + kk*32 + lq*8);
      #pragma unroll
      for (int n = 0; n < 4; n++)
        #pragma unroll
        for (int m = 0; m < 4; m++)
          acc[m][n] = MFMA16(af[m], bf[n], acc[m][n], 0,0,0);
    }
    if (pf){
      unsigned short* Aw = As + (cur^1)*9216;
      unsigned short* Bw = Bs + (cur^1)*9216;
      #pragma unroll
      for (int j = 0; j < 4; j++){
        *(short8*)(Aw + srow*72 + scol + j*8) = ra[j];
        *(short8*)(Bw + srow*72 + scol + j*8) = rb[j];
      }
    }
    __syncthreads();
    cur ^= 1;
  }

  // epilogue: stage C in LDS, coalesced write
  if (EPI == 2){
    float* Cs = (float*)SM;           // [128][130]
    #pragma unroll
    for (int n = 0; n < 4; n++){
      const int col = wn*64 + n*16 + l16;
      const float bv = bias[c0 + col];
      #pragma unroll
      for (int m = 0; m < 4; m++)
        #pragma unroll
        for (int r = 0; r < 4; r++)
          Cs[(wm*64 + m*16 + lq*4 + r)*130 + col] = acc[m][n][r] + bv;
    }
    __syncthreads();
    float* C = (float*)Cv;
    #pragma unroll
    for (int it = 0; it < 16; it++){
      const int idx = it*256 + tid;          // 128 rows x 32 float4
      const int row = idx >> 5, c4 = (idx & 31) << 2;
      *(float4*)(C + (r0 + row)*ldc + c0 + c4) = *(const float4*)(Cs + row*130 + c4);
    }
  } else {
    unsigned short* Cs = SM;          // [128][132]
    #pragma unroll
    for (int n = 0; n < 4; n++){
      const int col = wn*64 + n*16 + l16;
      const float bv = (EPI == 1) ? bias[c0 + col] : 0.f;
      #pragma unroll
      for (int m = 0; m < 4; m++)
        #pragma unroll
        for (int r = 0; r < 4; r++){
          float v = acc[m][n][r] + bv;
          if (EPI == 1) v = fmaxf(v, 0.f);
          Cs[(wm*64 + m*16 + lq*4 + r)*132 + col] = f2bf(v);
        }
    }
    __syncthreads();
    unsigned short* C = (unsigned short*)Cv;
    #pragma unroll
    for (int it = 0; it < 8; it++){
      const int idx = it*256 + tid;          // 128 rows x 16 short8
      const int row = idx >> 4, c8 = (idx & 15) << 3;
      *(short8*)(C + (r0 + row)*ldc + c0 + c8) = *(const short8*)(Cs + row*132 + c8);
    }
  }
}

extern "C" void kernel_launch(void* const* d_in, const int* in_sizes, int n_in,
                              void* d_out, int out_size, void* d_ws, size_t ws_size,
                              hipStream_t stream) {
  (void)n_in; (void)out_size;
  const float* x    = (const float*)d_in[0];
  const float* pos  = (const float*)d_in[1];
  const float* hWq  = (const float*)d_in[2];
  const float* hWk  = (const float*)d_in[3];
  const float* hWv  = (const float*)d_in[4];
  const float* hW1  = (const float*)d_in[5];
  const float* hb1  = (const float*)d_in[6];
  const float* hW2  = (const float*)d_in[7];
  const float* hb2  = (const float*)d_in[8];
  const float* oWq  = (const float*)d_in[9];
  const float* oWk  = (const float*)d_in[10];
  const float* oWv  = (const float*)d_in[11];
  const float* oW1  = (const float*)d_in[12];
  const float* ob1  = (const float*)d_in[13];
  const float* oW2  = (const float*)d_in[14];
  const float* ob2  = (const float*)d_in[15];

  unsigned short* WT  = (unsigned short*)d_ws;
  unsigned short* xpf = (unsigned short*)((char*)d_ws + XP_OFFB);
  float* out = (float*)d_out;

  const long long BT = in_sizes[0] / 256;   // 131072

  // chunk sizing: feats + qkv2 + ao + h1 rings = R*6656 bytes; keep L3-resident
  const size_t capB = (ws_size > FEATS_OFFB) ? (ws_size - FEATS_OFFB) : 0;
  long long R = (long long)(capB / 6656);
  if (R > 16384) R = 16384;
  if (R > BT) R = BT;
  R &= ~127LL;
  if (R < 128) R = 128;
  const long long FHSTR = R * 256;          // feats head-region stride (elems)

  unsigned short* feats = (unsigned short*)((char*)d_ws + FEATS_OFFB);
  unsigned short* qkv2  = (unsigned short*)((char*)feats + (size_t)R*4096);
  unsigned short* ao    = (unsigned short*)((char*)qkv2  + (size_t)R*1536);
  unsigned short* h1o   = (unsigned short*)((char*)ao    + (size_t)R*512);

  // weight transposes (bf16, [N][K])
  k_transpose<<<dim3(256,8),  256, 0, stream>>>(hWq, WT,                      256, 256, 65536, 196608);
  k_transpose<<<dim3(256,8),  256, 0, stream>>>(hWk, WT + 65536,              256, 256, 65536, 196608);
  k_transpose<<<dim3(256,8),  256, 0, stream>>>(hWv, WT + 131072,             256, 256, 65536, 196608);
  k_transpose<<<dim3(512,8),  256, 0, stream>>>(hW1, WT + W1T_OFF,            512, 256, 131072, 131072);
  k_transpose<<<dim3(256,8),  256, 0, stream>>>(hW2, WT + W2T_OFF,            256, 256, 65536, 65536);
  k_transpose<<<dim3(2048,1), 256, 0, stream>>>(oWq, WT + OQKV_OFF,           2048, 256, 0, 0);
  k_transpose<<<dim3(2048,1), 256, 0, stream>>>(oWk, WT + OQKV_OFF + 524288,  2048, 256, 0, 0);
  k_transpose<<<dim3(2048,1), 256, 0, stream>>>(oWv, WT + OQKV_OFF + 1048576, 2048, 256, 0, 0);
  k_transpose<<<dim3(2304,1), 256, 0, stream>>>(oW1, WT + OW1_OFF,            2304, 256, 0, 0);
  k_transpose<<<dim3(256,1),  256, 0, stream>>>(oW2, WT + OW2_OFF,            256, 256, 0, 0);

  k_xp<<<(int)(BT/8), 256, 0, stream>>>(x, pos, xpf);

  for (long long base = 0; base < BT; base += R) {
    const long long Rc = (BT - base < R) ? (BT - base) : R;
    const int mt64  = (int)(Rc / 64);
    const int mt128 = (int)(Rc / 128);

    k_head<<<dim3(mt64, 2), 512, 0, stream>>>(xpf + base*256, WT, hb1, hb2, feats, FHSTR);

    // QKV2: A = feats head-major, K=2048
    k_gemm<0><<<dim3(mt128, 6), 256, 0, stream>>>(
        feats, 0, 0, feats, 0, FHSTR,
        WT + OQKV_OFF, 2048, 2048, nullptr, qkv2, 768);

    k_attn2<<<mt64, 512, 0, stream>>>(qkv2, ao);

    // FFN1: A = [ao | feats head-major], K=2304
    k_gemm<1><<<dim3(mt128, 2), 256, 0, stream>>>(
        ao, 256, 256, feats, 0, FHSTR,
        WT + OW1_OFF, 2304, 2304, ob1, h1o, 256);

    // FFN2: A = h1o row-major, K=256
    k_gemm<2><<<dim3(mt128, 2), 256, 0, stream>>>(
        h1o, 256, 256, h1o, 256, 0,
        WT + OW2_OFF, 256, 256, ob2, out + base*256, 256);
  }
}

// Round 8
// 3170.897 us; speedup vs baseline: 1.8939x; 1.8939x over previous
//
#include <hip/hip_runtime.h>

typedef __attribute__((ext_vector_type(8))) short short8;
typedef __attribute__((ext_vector_type(4))) float f32x4;

#define MFMA16 __builtin_amdgcn_mfma_f32_16x16x32_bf16

__device__ __forceinline__ unsigned short f2bf(float f){
  union { float f; unsigned int u; } v; v.f = f;
  unsigned int u = v.u + 0x7fffu + ((v.u >> 16) & 1u);  // RNE
  return (unsigned short)(u >> 16);
}
__device__ __forceinline__ float lo2f(unsigned int u){ union { unsigned int u; float f; } v; v.u = u << 16; return v.f; }
__device__ __forceinline__ float hi2f(unsigned int u){ union { unsigned int u; float f; } v; v.u = u & 0xffff0000u; return v.f; }

// ---------------- ws layout (weights) ----------------
constexpr size_t WQKV_HSTR = 768*256;                       // per-head [768][256] rows: Q 0-255, K 256-511, V 512-767
constexpr size_t W1T_OFF   = 8*WQKV_HSTR;                   // 8 x [256][512]
constexpr size_t W1T_HSTR  = 512*256;
constexpr size_t W2T_OFF   = W1T_OFF + 8*W1T_HSTR;          // 8 x [256][256]
constexpr size_t W2T_HSTR  = 256*256;
constexpr size_t OQKV_OFF  = W2T_OFF + 8*W2T_HSTR;          // [768][2048]
constexpr size_t OW1_OFF   = OQKV_OFF + (size_t)768*2048;   // [256][2304]
constexpr size_t OW2_OFF   = OW1_OFF + (size_t)256*2304;    // [256][256]
constexpr size_t WT_ELEMS  = OW2_OFF + (size_t)256*256;
constexpr size_t XP_OFFB   = (WT_ELEMS*2 + 255) & ~(size_t)255;
constexpr size_t XP_BYTES  = (size_t)131072*256*2;          // xp: row-major [BT][256]
constexpr size_t FEATS_OFFB = XP_OFFB + XP_BYTES;

constexpr int LDX  = 264;   // xp tile stride (528B -> bank step 4)
constexpr int LDQ  = 776;   // qkv tile stride (1552B -> bank step 4)

// ---------------- prep: transpose weights to bf16 [N][K] ----------------
__global__ void k_transpose(const float* __restrict__ src, unsigned short* __restrict__ dst,
                            int K, int N, long long srcStride, long long dstStride){
  const int i = blockIdx.x*256 + threadIdx.x;
  const int b = blockIdx.y;
  const int n = i / K, k = i - n*K;
  dst[(size_t)b*dstStride + i] = f2bf(src[(size_t)b*srcStride + (size_t)k*N + n]);
}

// ---------------- xp = bf16(x + pos), row-major ----------------
__global__ void k_xp(const float* __restrict__ x, const float* __restrict__ pos,
                     unsigned short* __restrict__ xp){
  const size_t i = ((size_t)blockIdx.x*256 + threadIdx.x) * 8;
  const int colb = (int)(i & 255);
  const int t = (int)((i >> 8) & 7);
  float4 a0 = *(const float4*)(x + i);
  float4 a1 = *(const float4*)(x + i + 4);
  float4 p0 = *(const float4*)(pos + t*256 + colb);
  float4 p1 = *(const float4*)(pos + t*256 + colb + 4);
  short8 o;
  o[0]=(short)f2bf(a0.x+p0.x); o[1]=(short)f2bf(a0.y+p0.y);
  o[2]=(short)f2bf(a0.z+p0.z); o[3]=(short)f2bf(a0.w+p0.w);
  o[4]=(short)f2bf(a1.x+p1.x); o[5]=(short)f2bf(a1.y+p1.y);
  o[6]=(short)f2bf(a1.z+p1.z); o[7]=(short)f2bf(a1.w+p1.w);
  *(short8*)(xp + i) = o;
}

// ==================== per-head fused kernel (r2-proven) ====================
// grid (R/64, 8 heads), 512 threads = 8 waves. xp staged ONCE into LDS;
// all MFMA A-fragments from LDS; B panels from global (L2-hot).
__global__ __launch_bounds__(512, 2) void k_head(
    const unsigned short* __restrict__ xp,
    const unsigned short* __restrict__ WT,
    const float* __restrict__ hb1, const float* __restrict__ hb2,
    unsigned short* __restrict__ feats)
{
  __shared__ __align__(16) unsigned short xs[64*LDX];
  __shared__ __align__(16) unsigned short qs[64*LDQ];   // Q|K|V cols 0/256/512; later attn_out|h1
  __shared__ float aw[8][64];

  const int h    = blockIdx.y;
  const int r0   = blockIdx.x << 6;
  const int tid  = threadIdx.x;
  const int wave = tid >> 6;
  const int lane = tid & 63;
  const int l16  = lane & 15;
  const int lq   = lane >> 4;

  // load xp tile (64 x 256)
  {
    const int row = tid >> 3, c0 = (tid & 7) << 5;
    const short8* s = (const short8*)(xp + (size_t)(r0 + row)*256 + c0);
    short8* d = (short8*)(xs + row*LDX + c0);
    #pragma unroll
    for (int j = 0; j < 4; j++) d[j] = s[j];
  }
  __syncthreads();

  // QKV: [64,256] @ [256,768]; wave owns 96 cols
  {
    const unsigned short* W = WT + (size_t)h * WQKV_HSTR;
    f32x4 acc[4][6];
    #pragma unroll
    for (int m = 0; m < 4; m++)
      #pragma unroll
      for (int n = 0; n < 6; n++) acc[m][n] = (f32x4){0.f,0.f,0.f,0.f};
    #pragma unroll
    for (int kk = 0; kk < 8; kk++){
      const int ko = (kk << 5) + (lq << 3);
      short8 a[4];
      #pragma unroll
      for (int m = 0; m < 4; m++)
        a[m] = *(const short8*)(xs + (m*16 + l16)*LDX + ko);
      #pragma unroll
      for (int n = 0; n < 6; n++){
        const int col = wave*96 + n*16 + l16;
        short8 b = *(const short8*)(W + (size_t)col*256 + ko);
        #pragma unroll
        for (int m = 0; m < 4; m++)
          acc[m][n] = MFMA16(a[m], b, acc[m][n], 0, 0, 0);
      }
    }
    #pragma unroll
    for (int n = 0; n < 6; n++){
      const int col = wave*96 + n*16 + l16;
      #pragma unroll
      for (int m = 0; m < 4; m++)
        #pragma unroll
        for (int r = 0; r < 4; r++)
          qs[(m*16 + lq*4 + r)*LDQ + col] = f2bf(acc[m][n][r]);
    }
  }
  __syncthreads();

  // attention scores + causal softmax; wave <-> batch group, lane = (t,s)
  {
    const int t = lane >> 3, s = lane & 7;
    const unsigned short* Qr = qs + (wave*8 + t)*LDQ;
    const unsigned short* Kr = qs + (wave*8 + s)*LDQ + 256;
    float e = 0.f;
    #pragma unroll
    for (int c = 0; c < 256; c += 8){
      union { short8 v; unsigned int u[4]; } qa, kb;
      qa.v = *(const short8*)(Qr + c);
      kb.v = *(const short8*)(Kr + c);
      #pragma unroll
      for (int j = 0; j < 4; j++){
        e = fmaf(lo2f(qa.u[j]), lo2f(kb.u[j]), e);
        e = fmaf(hi2f(qa.u[j]), hi2f(kb.u[j]), e);
      }
    }
    e *= 0.0625f;                    // 1/sqrt(256)
    if (s > t) e = -1e30f;           // causal
    float mx = fmaxf(e, __shfl_xor(e, 1));
    mx = fmaxf(mx, __shfl_xor(mx, 2));
    mx = fmaxf(mx, __shfl_xor(mx, 4));
    float p = (s <= t) ? __expf(e - mx) : 0.f;
    float sum = p;
    sum += __shfl_xor(sum, 1);
    sum += __shfl_xor(sum, 2);
    sum += __shfl_xor(sum, 4);
    aw[wave][lane] = p / sum;
  }
  __syncthreads();

  // attn @ V -> qs cols 0..255 (overwrites Q)
  {
    const int t = lane >> 3, c8 = lane & 7;
    float o[32];
    #pragma unroll
    for (int j = 0; j < 32; j++) o[j] = 0.f;
    #pragma unroll
    for (int s = 0; s < 8; s++){
      const float w = aw[wave][t*8 + s];
      const unsigned short* Vr = qs + (wave*8 + s)*LDQ + 512 + (c8 << 5);
      #pragma unroll
      for (int jj = 0; jj < 4; jj++){
        union { short8 v; unsigned int u[4]; } vv;
        vv.v = *(const short8*)(Vr + jj*8);
        #pragma unroll
        for (int q = 0; q < 4; q++){
          o[jj*8 + 2*q]     = fmaf(w, lo2f(vv.u[q]), o[jj*8 + 2*q]);
          o[jj*8 + 2*q + 1] = fmaf(w, hi2f(vv.u[q]), o[jj*8 + 2*q + 1]);
        }
      }
    }
    unsigned short* Or = qs + (wave*8 + t)*LDQ + (c8 << 5);
    #pragma unroll
    for (int j = 0; j < 32; j++) Or[j] = f2bf(o[j]);
  }
  __syncthreads();

  // FFN1: cat(attn_out, xp) [64,512] @ [512,256]; wave owns 32 cols
  {
    const unsigned short* W = WT + W1T_OFF + (size_t)h * W1T_HSTR;
    f32x4 acc[4][2];
    #pragma unroll
    for (int m = 0; m < 4; m++){ acc[m][0] = (f32x4){0.f,0.f,0.f,0.f}; acc[m][1] = (f32x4){0.f,0.f,0.f,0.f}; }
    #pragma unroll
    for (int kk = 0; kk < 16; kk++){
      const int ko = (kk << 5) + (lq << 3);
      short8 a[4];
      #pragma unroll
      for (int m = 0; m < 4; m++)
        a[m] = (kk < 8) ? *(const short8*)(qs + (m*16 + l16)*LDQ + ko)
                        : *(const short8*)(xs + (m*16 + l16)*LDX + (ko - 256));
      #pragma unroll
      for (int n = 0; n < 2; n++){
        const int col = (wave << 5) + (n << 4) + l16;
        short8 b = *(const short8*)(W + (size_t)col*512 + ko);
        #pragma unroll
        for (int m = 0; m < 4; m++)
          acc[m][n] = MFMA16(a[m], b, acc[m][n], 0, 0, 0);
      }
    }
    #pragma unroll
    for (int n = 0; n < 2; n++){
      const int col = (wave << 5) + (n << 4) + l16;
      const float bv = hb1[(h << 8) + col];
      #pragma unroll
      for (int m = 0; m < 4; m++)
        #pragma unroll
        for (int r = 0; r < 4; r++)
          qs[(m*16 + lq*4 + r)*LDQ + 256 + col] = f2bf(fmaxf(acc[m][n][r] + bv, 0.f));
    }
  }
  __syncthreads();

  // FFN2: h1 [64,256] @ [256,256] -> feats slice
  {
    const unsigned short* W = WT + W2T_OFF + (size_t)h * W2T_HSTR;
    f32x4 acc[4][2];
    #pragma unroll
    for (int m = 0; m < 4; m++){ acc[m][0] = (f32x4){0.f,0.f,0.f,0.f}; acc[m][1] = (f32x4){0.f,0.f,0.f,0.f}; }
    #pragma unroll
    for (int kk = 0; kk < 8; kk++){
      const int ko = (kk << 5) + (lq << 3);
      short8 a[4];
      #pragma unroll
      for (int m = 0; m < 4; m++)
        a[m] = *(const short8*)(qs + (m*16 + l16)*LDQ + 256 + ko);
      #pragma unroll
      for (int n = 0; n < 2; n++){
        const int col = (wave << 5) + (n << 4) + l16;
        short8 b = *(const short8*)(W + (size_t)col*256 + ko);
        #pragma unroll
        for (int m = 0; m < 4; m++)
          acc[m][n] = MFMA16(a[m], b, acc[m][n], 0, 0, 0);
      }
    }
    #pragma unroll
    for (int n = 0; n < 2; n++){
      const int col = (wave << 5) + (n << 4) + l16;
      const float bv = hb2[(h << 8) + col];
      #pragma unroll
      for (int m = 0; m < 4; m++)
        #pragma unroll
        for (int r = 0; r < 4; r++)
          feats[(size_t)(r0 + m*16 + lq*4 + r)*2048 + (h << 8) + col] = f2bf(acc[m][n][r] + bv);
    }
  }
}

// ==================== output-layer attention ====================
__global__ __launch_bounds__(512, 4) void k_attn2(
    const unsigned short* __restrict__ qkv2, unsigned short* __restrict__ ao)
{
  __shared__ float aw[8][64];
  const int r0   = blockIdx.x * 64;
  const int tid  = threadIdx.x;
  const int wave = tid >> 6;
  const int lane = tid & 63;
  const int g = wave;
  {
    const int t = lane >> 3, s = lane & 7;
    const unsigned short* Qr = qkv2 + (size_t)(r0 + g*8 + t)*768;
    const unsigned short* Kr = qkv2 + (size_t)(r0 + g*8 + s)*768 + 256;
    float e = 0.f;
    #pragma unroll
    for (int c = 0; c < 256; c += 8){
      union { short8 v; unsigned int u[4]; } qa, kb;
      qa.v = *(const short8*)(Qr + c);
      kb.v = *(const short8*)(Kr + c);
      #pragma unroll
      for (int j = 0; j < 4; j++){
        e = fmaf(lo2f(qa.u[j]), lo2f(kb.u[j]), e);
        e = fmaf(hi2f(qa.u[j]), hi2f(kb.u[j]), e);
      }
    }
    e *= 0.0625f;
    if (s > t) e = -1e30f;
    float mx = fmaxf(e, __shfl_xor(e, 1));
    mx = fmaxf(mx, __shfl_xor(mx, 2));
    mx = fmaxf(mx, __shfl_xor(mx, 4));
    float p = (s <= t) ? __expf(e - mx) : 0.f;
    float sum = p;
    sum += __shfl_xor(sum, 1);
    sum += __shfl_xor(sum, 2);
    sum += __shfl_xor(sum, 4);
    aw[g][lane] = p / sum;
  }
  __syncthreads();
  {
    const int t = lane >> 3, c8 = lane & 7;
    float o[32];
    #pragma unroll
    for (int j = 0; j < 32; j++) o[j] = 0.f;
    #pragma unroll
    for (int s = 0; s < 8; s++){
      const float w = aw[g][t*8 + s];
      const unsigned short* Vr = qkv2 + (size_t)(r0 + g*8 + s)*768 + 512 + (c8 << 5);
      #pragma unroll
      for (int jj = 0; jj < 4; jj++){
        union { short8 v; unsigned int u[4]; } vv;
        vv.v = *(const short8*)(Vr + jj*8);
        #pragma unroll
        for (int q = 0; q < 4; q++){
          o[jj*8 + 2*q]     = fmaf(w, lo2f(vv.u[q]), o[jj*8 + 2*q]);
          o[jj*8 + 2*q + 1] = fmaf(w, hi2f(vv.u[q]), o[jj*8 + 2*q + 1]);
        }
      }
    }
    unsigned short* Or = ao + (size_t)(r0 + g*8 + t)*256 + (c8 << 5);
    #pragma unroll
    for (int jj = 0; jj < 4; jj++){
      short8 v;
      #pragma unroll
      for (int q = 0; q < 8; q++) v[q] = (short)f2bf(o[jj*8 + q]);
      *(short8*)(Or + jj*8) = v;
    }
  }
}

// ==================== tiled GEMM: C[M,N] = A @ B^T ====================
// A: k<K1 from A1 (row-major lda1); k>=K1 from A2 (row-major lda2).
// 128x128 tile, 4 waves (2x2), BK=64, reg-staged double-buffered LDS.
// EPI: 0 = bf16 store; 1 = bias+relu bf16; 2 = bias f32.
template<int EPI>
__global__ __launch_bounds__(256, 2) void k_gemm(
    const unsigned short* __restrict__ A1, long long lda1, int K1,
    const unsigned short* __restrict__ A2, long long lda2,
    const unsigned short* __restrict__ B, long long ldb, int K,
    const float* __restrict__ bias,
    void* __restrict__ Cv, long long ldc)
{
  __shared__ __align__(16) unsigned short SM[36864];   // 72KB: As[2][128*72] | Bs[2][128*72]
  unsigned short* As = SM;
  unsigned short* Bs = SM + 18432;

  const int tid  = threadIdx.x;
  const int wave = tid >> 6, lane = tid & 63;
  const int l16  = lane & 15, lq = lane >> 4;
  const int wm   = wave >> 1, wn = wave & 1;
  const size_t r0 = (size_t)blockIdx.x * 128;
  const int    c0 = blockIdx.y * 128;
  const int srow = tid >> 1, scol = (tid & 1) * 32;   // staging: 32 elems/thread

  f32x4 acc[4][4];
  #pragma unroll
  for (int m = 0; m < 4; m++)
    #pragma unroll
    for (int n = 0; n < 4; n++) acc[m][n] = (f32x4){0.f,0.f,0.f,0.f};

  const int KS = K >> 6;

  auto srcA = [&](int k0) -> const unsigned short* {
    if (k0 < K1) return A1 + (r0 + srow)*lda1 + k0 + scol;
    return A2 + (r0 + srow)*lda2 + (k0 - K1) + scol;
  };

  // prologue: stage k0=0 into buf 0
  {
    const unsigned short* sa = srcA(0);
    const unsigned short* sb = B + (size_t)(c0 + srow)*ldb + scol;
    #pragma unroll
    for (int j = 0; j < 4; j++){
      *(short8*)(As + srow*72 + scol + j*8) = *(const short8*)(sa + j*8);
      *(short8*)(Bs + srow*72 + scol + j*8) = *(const short8*)(sb + j*8);
    }
  }
  __syncthreads();

  int cur = 0;
  for (int s2 = 0; s2 < KS; s2++){
    short8 ra[4], rb[4];
    const bool pf = (s2 + 1 < KS);
    if (pf){
      const int k0 = (s2 + 1) << 6;
      const unsigned short* sa = srcA(k0);
      const unsigned short* sb = B + (size_t)(c0 + srow)*ldb + k0 + scol;
      #pragma unroll
      for (int j = 0; j < 4; j++){ ra[j] = *(const short8*)(sa + j*8); rb[j] = *(const short8*)(sb + j*8); }
    }
    const unsigned short* Ab = As + cur*9216;
    const unsigned short* Bb = Bs + cur*9216;
    #pragma unroll
    for (int kk = 0; kk < 2; kk++){
      short8 af[4], bf[4];
      #pragma unroll
      for (int m = 0; m < 4; m++) af[m] = *(const short8*)(Ab + (wm*64 + m*16 + l16)*72 + kk*32 + lq*8);
      #pragma unroll
      for (int n = 0; n < 4; n++) bf[n] = *(const short8*)(Bb + (wn*64 + n*16 + l16)*72 + kk*32 + lq*8);
      #pragma unroll
      for (int n = 0; n < 4; n++)
        #pragma unroll
        for (int m = 0; m < 4; m++)
          acc[m][n] = MFMA16(af[m], bf[n], acc[m][n], 0,0,0);
    }
    if (pf){
      unsigned short* Aw = As + (cur^1)*9216;
      unsigned short* Bw = Bs + (cur^1)*9216;
      #pragma unroll
      for (int j = 0; j < 4; j++){
        *(short8*)(Aw + srow*72 + scol + j*8) = ra[j];
        *(short8*)(Bw + srow*72 + scol + j*8) = rb[j];
      }
    }
    __syncthreads();
    cur ^= 1;
  }

  // epilogue: stage C in LDS, coalesced write
  if (EPI == 2){
    float* Cs = (float*)SM;           // [128][130]
    #pragma unroll
    for (int n = 0; n < 4; n++){
      const int col = wn*64 + n*16 + l16;
      const float bv = bias[c0 + col];
      #pragma unroll
      for (int m = 0; m < 4; m++)
        #pragma unroll
        for (int r = 0; r < 4; r++)
          Cs[(wm*64 + m*16 + lq*4 + r)*130 + col] = acc[m][n][r] + bv;
    }
    __syncthreads();
    float* C = (float*)Cv;
    #pragma unroll
    for (int it = 0; it < 16; it++){
      const int idx = it*256 + tid;          // 128 rows x 32 float4
      const int row = idx >> 5, c4 = (idx & 31) << 2;
      *(float4*)(C + (r0 + row)*ldc + c0 + c4) = *(const float4*)(Cs + row*130 + c4);
    }
  } else {
    unsigned short* Cs = SM;          // [128][132]
    #pragma unroll
    for (int n = 0; n < 4; n++){
      const int col = wn*64 + n*16 + l16;
      const float bv = (EPI == 1) ? bias[c0 + col] : 0.f;
      #pragma unroll
      for (int m = 0; m < 4; m++)
        #pragma unroll
        for (int r = 0; r < 4; r++){
          float v = acc[m][n][r] + bv;
          if (EPI == 1) v = fmaxf(v, 0.f);
          Cs[(wm*64 + m*16 + lq*4 + r)*132 + col] = f2bf(v);
        }
    }
    __syncthreads();
    unsigned short* C = (unsigned short*)Cv;
    #pragma unroll
    for (int it = 0; it < 8; it++){
      const int idx = it*256 + tid;          // 128 rows x 16 short8
      const int row = idx >> 4, c8 = (idx & 15) << 3;
      *(short8*)(C + (r0 + row)*ldc + c0 + c8) = *(const short8*)(Cs + row*132 + c8);
    }
  }
}

extern "C" void kernel_launch(void* const* d_in, const int* in_sizes, int n_in,
                              void* d_out, int out_size, void* d_ws, size_t ws_size,
                              hipStream_t stream) {
  (void)n_in; (void)out_size;
  const float* x    = (const float*)d_in[0];
  const float* pos  = (const float*)d_in[1];
  const float* hWq  = (const float*)d_in[2];
  const float* hWk  = (const float*)d_in[3];
  const float* hWv  = (const float*)d_in[4];
  const float* hW1  = (const float*)d_in[5];
  const float* hb1  = (const float*)d_in[6];
  const float* hW2  = (const float*)d_in[7];
  const float* hb2  = (const float*)d_in[8];
  const float* oWq  = (const float*)d_in[9];
  const float* oWk  = (const float*)d_in[10];
  const float* oWv  = (const float*)d_in[11];
  const float* oW1  = (const float*)d_in[12];
  const float* ob1  = (const float*)d_in[13];
  const float* oW2  = (const float*)d_in[14];
  const float* ob2  = (const float*)d_in[15];

  unsigned short* WT  = (unsigned short*)d_ws;
  unsigned short* xp  = (unsigned short*)((char*)d_ws + XP_OFFB);
  float* out = (float*)d_out;

  const long long BT = in_sizes[0] / 256;   // 131072

  // chunk sizing: feats + qkv2 + ao + h1 rings = R*6656 bytes; keep L3-resident
  const size_t capB = (ws_size > FEATS_OFFB) ? (ws_size - FEATS_OFFB) : 0;
  long long R = (long long)(capB / 6656);
  if (R > 16384) R = 16384;
  if (R > BT) R = BT;
  R &= ~127LL;
  if (R < 128) R = 128;

  unsigned short* feats = (unsigned short*)((char*)d_ws + FEATS_OFFB);
  unsigned short* qkv2  = (unsigned short*)((char*)feats + (size_t)R*4096);
  unsigned short* ao    = (unsigned short*)((char*)qkv2  + (size_t)R*1536);
  unsigned short* h1o   = (unsigned short*)((char*)ao    + (size_t)R*512);

  // weight transposes (bf16, [N][K])
  k_transpose<<<dim3(256,8),  256, 0, stream>>>(hWq, WT,                      256, 256, 65536, 196608);
  k_transpose<<<dim3(256,8),  256, 0, stream>>>(hWk, WT + 65536,              256, 256, 65536, 196608);
  k_transpose<<<dim3(256,8),  256, 0, stream>>>(hWv, WT + 131072,             256, 256, 65536, 196608);
  k_transpose<<<dim3(512,8),  256, 0, stream>>>(hW1, WT + W1T_OFF,            512, 256, 131072, 131072);
  k_transpose<<<dim3(256,8),  256, 0, stream>>>(hW2, WT + W2T_OFF,            256, 256, 65536, 65536);
  k_transpose<<<dim3(2048,1), 256, 0, stream>>>(oWq, WT + OQKV_OFF,           2048, 256, 0, 0);
  k_transpose<<<dim3(2048,1), 256, 0, stream>>>(oWk, WT + OQKV_OFF + 524288,  2048, 256, 0, 0);
  k_transpose<<<dim3(2048,1), 256, 0, stream>>>(oWv, WT + OQKV_OFF + 1048576, 2048, 256, 0, 0);
  k_transpose<<<dim3(2304,1), 256, 0, stream>>>(oW1, WT + OW1_OFF,            2304, 256, 0, 0);
  k_transpose<<<dim3(256,1),  256, 0, stream>>>(oW2, WT + OW2_OFF,            256, 256, 0, 0);

  k_xp<<<(int)(BT/8), 256, 0, stream>>>(x, pos, xp);

  for (long long base = 0; base < BT; base += R) {
    const long long Rc = (BT - base < R) ? (BT - base) : R;
    const int mt64  = (int)(Rc / 64);
    const int mt128 = (int)(Rc / 128);

    k_head<<<dim3(mt64, 8), 512, 0, stream>>>(xp + base*256, WT, hb1, hb2, feats);

    // QKV2: A = feats [R][2048], K=2048
    k_gemm<0><<<dim3(mt128, 6), 256, 0, stream>>>(
        feats, 2048, 1<<30, feats, 2048,
        WT + OQKV_OFF, 2048, 2048, nullptr, qkv2, 768);

    k_attn2<<<mt64, 512, 0, stream>>>(qkv2, ao);

    // FFN1: A = [ao | feats], K=2304
    k_gemm<1><<<dim3(mt128, 2), 256, 0, stream>>>(
        ao, 256, 256, feats, 2048,
        WT + OW1_OFF, 2304, 2304, ob1, h1o, 256);

    // FFN2: A = h1o, K=256
    k_gemm<2><<<dim3(mt128, 2), 256, 0, stream>>>(
        h1o, 256, 256, h1o, 256,
        WT + OW2_OFF, 256, 256, ob2, out + base*256, 256);
  }
}